// Round 3
// baseline (3346.400 us; speedup 1.0000x reference)
//
#include <hip/hip_runtime.h>
#include <hip/hip_bf16.h>
#include <math.h>

// Problem constants (MambaEncoder: L=2, B=2, S=1024, D=512) — f32 in, f32 out.
#define B_ 2
#define S_ 1024
#define D_ 512
#define DH_ 256
#define DI_ 512
#define N_ 16
#define R_ 16
#define M_ 2048   // B_*S_

// ---------------------------------------------------------------------------
// Generic GEMM: C[m,n] = sum_k A[m*lda+k] * W[n*ldw+k]  (+bias[n]) (+res[m*ldc+n])
// ep==1: softplus epilogue. res may alias C (same element read-then-write by
// the owning thread only — safe).
__global__ __launch_bounds__(256) void k_gemm(
    const float* __restrict__ A, int lda,
    const float* __restrict__ W, int ldw,
    const float* __restrict__ bias,
    const float* res,
    float* C, int ldc,
    int M, int Nn, int Kk, int ep) {
  __shared__ float As[64][17];
  __shared__ float Ws[64][17];
  const int bm = blockIdx.y * 64, bn = blockIdx.x * 64;
  const int tid = threadIdx.x;
  const int tr = tid >> 4, tc = tid & 15;
  float acc[4][4];
#pragma unroll
  for (int i = 0; i < 4; i++)
#pragma unroll
    for (int j = 0; j < 4; j++) acc[i][j] = 0.f;

  for (int k0 = 0; k0 < Kk; k0 += 16) {
#pragma unroll
    for (int i = 0; i < 4; i++) {
      int idx = tid + i * 256;
      int r = idx >> 4, c = idx & 15;
      int gk = k0 + c;
      int gm = bm + r;
      As[r][c] = (gm < M && gk < Kk) ? A[(size_t)gm * lda + gk] : 0.f;
      int gn = bn + r;
      Ws[r][c] = (gn < Nn && gk < Kk) ? W[(size_t)gn * ldw + gk] : 0.f;
    }
    __syncthreads();
#pragma unroll
    for (int kk = 0; kk < 16; kk++) {
      float a0[4], w0[4];
#pragma unroll
      for (int i = 0; i < 4; i++) a0[i] = As[tr * 4 + i][kk];
#pragma unroll
      for (int j = 0; j < 4; j++) w0[j] = Ws[tc * 4 + j][kk];
#pragma unroll
      for (int i = 0; i < 4; i++)
#pragma unroll
        for (int j = 0; j < 4; j++) acc[i][j] += a0[i] * w0[j];
    }
    __syncthreads();
  }
#pragma unroll
  for (int i = 0; i < 4; i++) {
    int gm = bm + tr * 4 + i;
    if (gm >= M) continue;
#pragma unroll
    for (int j = 0; j < 4; j++) {
      int gn = bn + tc * 4 + j;
      if (gn >= Nn) continue;
      float v = acc[i][j];
      if (bias) v += bias[gn];
      if (res) v += res[(size_t)gm * ldc + gn];
      if (ep == 1) v = (v > 20.f) ? v : log1pf(expf(v));
      C[(size_t)gm * ldc + gn] = v;
    }
  }
}

// ---------------------------------------------------------------------------
// LayerNorm over last dim C (256 or 512). One 256-thread block per row. f32 out.
__global__ __launch_bounds__(256) void k_ln(const float* __restrict__ X,
                                            const float* __restrict__ g,
                                            const float* __restrict__ bta,
                                            float* __restrict__ Y, int C) {
  const int row = blockIdx.x;
  const float* xr = X + (size_t)row * C;
  const int tid = threadIdx.x;
  const int per = C >> 8;  // 1 or 2
  float vals[2];
  float sum = 0.f, sumsq = 0.f;
  for (int i = 0; i < per; i++) {
    float v = xr[tid + i * 256];
    vals[i] = v;
    sum += v;
    sumsq += v * v;
  }
#pragma unroll
  for (int off = 1; off < 64; off <<= 1) {
    sum += __shfl_xor(sum, off, 64);
    sumsq += __shfl_xor(sumsq, off, 64);
  }
  __shared__ float s1[4], s2[4];
  int wid = tid >> 6, lane = tid & 63;
  if (lane == 0) { s1[wid] = sum; s2[wid] = sumsq; }
  __syncthreads();
  if (tid == 0) {
    float a = 0.f, c2 = 0.f;
    for (int w = 0; w < 4; w++) { a += s1[w]; c2 += s2[w]; }
    s1[0] = a; s2[0] = c2;
  }
  __syncthreads();
  float mean = s1[0] / (float)C;
  float var = s2[0] / (float)C - mean * mean;
  float rstd = rsqrtf(var + 1e-5f);
  for (int i = 0; i < per; i++) {
    int c = tid + i * 256;
    Y[(size_t)row * C + c] = (vals[i] - mean) * rstd * g[c] + bta[c];
  }
}

// ---------------------------------------------------------------------------
// Split xp (M,512) into u_f (M,256) = xp[:, :256] and u_b = flip_S(xp[:, 256:]).
__global__ __launch_bounds__(256) void k_split(const float* __restrict__ xp,
                                               float* __restrict__ uf,
                                               float* __restrict__ ub) {
  int idx = blockIdx.x * 256 + threadIdx.x;  // over M_*DH_
  if (idx >= M_ * DH_) return;
  int d = idx & (DH_ - 1);
  int row = idx >> 8;          // b*S+t
  int b = row >> 10, t = row & (S_ - 1);
  uf[idx] = xp[(size_t)row * D_ + d];
  ub[idx] = xp[((size_t)(b * S_ + (S_ - 1 - t))) * D_ + DH_ + d];
}

// Concat with back-flip: ycat (M,512) = [out_f[t], out_b[S-1-t]]
__global__ __launch_bounds__(256) void k_concat(const float* __restrict__ of,
                                                const float* __restrict__ ob,
                                                float* __restrict__ ycat) {
  int idx = blockIdx.x * 256 + threadIdx.x;  // over M_*DH_
  if (idx >= M_ * DH_) return;
  int d = idx & (DH_ - 1);
  int row = idx >> 8;
  int b = row >> 10, t = row & (S_ - 1);
  ycat[(size_t)row * D_ + d] = of[idx];
  ycat[(size_t)row * D_ + DH_ + d] = ob[((size_t)(b * S_ + (S_ - 1 - t))) * DH_ + d];
}

// ---------------------------------------------------------------------------
// Causal depthwise conv (K=4) + SiLU. Input: xz cols [0,512). Output xcv (M,512).
__global__ __launch_bounds__(256) void k_conv(const float* __restrict__ xz,
                                              const float* __restrict__ w,
                                              const float* __restrict__ cb,
                                              float* __restrict__ out) {
  int idx = blockIdx.x * 256 + threadIdx.x;  // over M_*DI_
  if (idx >= M_ * DI_) return;
  int d = idx & (DI_ - 1);
  int row = idx >> 9;
  int t = row & (S_ - 1);
  float acc = cb[d];
#pragma unroll
  for (int k = 0; k < 4; k++) {
    int dt_ = k - 3;
    if (t + dt_ >= 0)
      acc += w[d * 4 + k] * xz[(size_t)(row + dt_) * 1024 + d];
  }
  out[idx] = acc / (1.f + __expf(-acc));  // silu
}

// ---------------------------------------------------------------------------
// SSM scan, one thread per (b,d). dt in xz cols [0,512), z in cols [512,1024).
// y = (scan_out + xc*Dp) * silu(z) written IN-PLACE over the dt region of xz
// (thread (b,d) is the only reader/writer of xz[row,d], write follows reads).
__global__ __launch_bounds__(256) void k_scan(
    float* __restrict__ xz,          // (M,1024): dt | z ; y overwrites dt
    const float* __restrict__ dbl,   // (M,48): [dt_raw(16) | B(16) | C(16)]
    const float* __restrict__ xc,    // (M,512) conv output
    const float* __restrict__ A_log, // (512,16)
    const float* __restrict__ Dp,    // (512)
    int unused)
{
  int b = blockIdx.x >> 1;
  int d = (blockIdx.x & 1) * 256 + threadIdx.x;
  float Av[N_];
#pragma unroll
  for (int n = 0; n < N_; n++) Av[n] = -__expf(A_log[d * N_ + n]);
  float Dd = Dp[d];
  float h[N_];
#pragma unroll
  for (int n = 0; n < N_; n++) h[n] = 0.f;

  for (int t = 0; t < S_; t++) {
    size_t row = (size_t)b * S_ + t;
    float dtv = xz[row * 1024 + d];
    float xv = xc[row * 512 + d];
    float zv = xz[row * 1024 + 512 + d];
    float dtx = dtv * xv;
    float acc = 0.f;
#pragma unroll
    for (int n = 0; n < N_; n++) {
      float bn = dbl[row * 48 + 16 + n];
      float cn = dbl[row * 48 + 32 + n];
      h[n] = __expf(dtv * Av[n]) * h[n] + dtx * bn;
      acc += h[n] * cn;
    }
    float sil = zv / (1.f + __expf(-zv));
    xz[row * 1024 + d] = (acc + xv * Dd) * sil;  // in-place y
  }
}

// ---------------------------------------------------------------------------
extern "C" void kernel_launch(void* const* d_in, const int* in_sizes, int n_in,
                              void* d_out, int out_size, void* d_ws, size_t ws_size,
                              hipStream_t stream) {
  // f32 inputs (proven: bf16 misread produced NaN; f32 read produces finite).
  const float* x     = (const float*)d_in[0];
  const float* ln_g  = (const float*)d_in[1];
  const float* ln_b  = (const float*)d_in[2];
  const float* inW   = (const float*)d_in[3];
  const float* convW = (const float*)d_in[4];
  const float* convB = (const float*)d_in[5];
  const float* xprojW= (const float*)d_in[6];
  const float* dtW   = (const float*)d_in[7];
  const float* dtB   = (const float*)d_in[8];
  const float* A_log = (const float*)d_in[9];
  const float* Dp    = (const float*)d_in[10];
  const float* outW  = (const float*)d_in[11];
  const float* ipW   = (const float*)d_in[12];
  const float* ipB   = (const float*)d_in[13];
  const float* opW   = (const float*)d_in[14];
  const float* opB   = (const float*)d_in[15];
  const float* fln_g = (const float*)d_in[16];
  const float* fln_b = (const float*)d_in[17];
  float* out = (float*)d_out;  // reference output dtype = float32

  // ---- workspace (floats, ~25.6 MB total) ----
  float* w = (float*)d_ws;
  float* xz    = w;  w += (size_t)M_ * 1024;   // dt|z, scan y in-place in cols [0,512)
  float* h_cur = w;  w += (size_t)M_ * D_;
  float* xp    = w;  w += (size_t)M_ * D_;     // also xn (first half) and ycat
  float* u_f   = w;  w += (size_t)M_ * DH_;    // o_f in-place
  float* u_b   = w;  w += (size_t)M_ * DH_;    // o_b in-place
  float* xcv   = w;  w += (size_t)M_ * DI_;
  float* dbl   = w;  w += (size_t)M_ * 48;
  float* xn    = xp;   // xp free during the j-loop (after split, before concat)
  float* ycat  = xp;

  for (int li = 0; li < 2; li++) {
    // xp = h @ ipW[li].T + ipB[li]   (layer 0 reads x directly)
    const float* hin = (li == 0) ? x : h_cur;
    k_gemm<<<dim3(D_ / 64, M_ / 64), 256, 0, stream>>>(
        hin, D_, ipW + (size_t)li * D_ * D_, D_, ipB + (size_t)li * D_,
        nullptr, xp, D_, M_, D_, D_, 0);
    k_split<<<(M_ * DH_ + 255) / 256, 256, 0, stream>>>(xp, u_f, u_b);

    for (int j = 0; j < 2; j++) {
      size_t wi = (size_t)li * 2 + j;
      float* u = (j == 0) ? u_f : u_b;
      // xn = LN(u)
      k_ln<<<M_, 256, 0, stream>>>(u, ln_g + wi * DH_, ln_b + wi * DH_, xn, DH_);
      // xz = xn @ inW.T   (M,1024) = [xc | z]
      k_gemm<<<dim3(1024 / 64, M_ / 64), 256, 0, stream>>>(
          xn, DH_, inW + wi * 1024 * DH_, DH_, nullptr, nullptr, xz, 1024,
          M_, 1024, DH_, 0);
      // xcv = silu(causal_conv(xz[:, :512]))
      k_conv<<<(M_ * DI_ + 255) / 256, 256, 0, stream>>>(
          xz, convW + wi * DI_ * 4, convB + wi * DI_, xcv);
      // dbl = xcv @ xprojW.T  (M,48)
      k_gemm<<<dim3(1, M_ / 64), 256, 0, stream>>>(
          xcv, DI_, xprojW + wi * 48 * DI_, DI_, nullptr, nullptr, dbl, 48,
          M_, 48, DI_, 0);
      // dt = softplus(dbl[:, :16] @ dtW.T + dtB) -> xz cols [0,512) (ldc=1024)
      k_gemm<<<dim3(DI_ / 64, M_ / 64), 256, 0, stream>>>(
          dbl, 48, dtW + wi * DI_ * R_, R_, dtB + wi * DI_, nullptr, xz, 1024,
          M_, DI_, R_, 1);
      // scan: y written in-place over dt region of xz
      k_scan<<<B_ * 2, 256, 0, stream>>>(xz, dbl, xcv, A_log + wi * DI_ * N_,
                                         Dp + wi * DI_, 0);
      // u = u + y @ outW.T   (in-place residual; A = xz with lda=1024)
      k_gemm<<<dim3(DH_ / 64, M_ / 64), 256, 0, stream>>>(
          xz, 1024, outW + wi * DH_ * DI_, DI_, nullptr, u, u, DH_,
          M_, DH_, DI_, 0);
    }
    // ycat = [o_f, flip(o_b)]
    k_concat<<<(M_ * DH_ + 255) / 256, 256, 0, stream>>>(u_f, u_b, ycat);
    // h = ycat @ opW.T + opB
    k_gemm<<<dim3(D_ / 64, M_ / 64), 256, 0, stream>>>(
        ycat, D_, opW + (size_t)li * D_ * D_, D_, opB + (size_t)li * D_,
        nullptr, h_cur, D_, M_, D_, D_, 0);
  }
  // final LN -> f32 out
  k_ln<<<M_, 256, 0, stream>>>(h_cur, fln_g, fln_b, out, D_);
}

// Round 4
// 1363.600 us; speedup vs baseline: 2.4541x; 2.4541x over previous
//
#include <hip/hip_runtime.h>
#include <hip/hip_bf16.h>
#include <math.h>

// Problem constants (MambaEncoder: L=2, B=2, S=1024, D=512) — f32 in, f32 out.
#define B_ 2
#define S_ 1024
#define D_ 512
#define DH_ 256
#define DI_ 512
#define N_ 16
#define R_ 16
#define M_ 2048   // B_*S_
#define T_ 16     // scan chunk length
#define CN_ 64    // chunks per sequence (T_*CN_ == S_)

// ---------------------------------------------------------------------------
// Generic GEMM: C[m,n] = sum_k A[m*lda+k] * W[n*ldw+k]  (+bias[n]) (+res[m*ldc+n])
// ep==1: softplus epilogue. res may alias C (same element, owning thread only).
__global__ __launch_bounds__(256) void k_gemm(
    const float* __restrict__ A, int lda,
    const float* __restrict__ W, int ldw,
    const float* __restrict__ bias,
    const float* res,
    float* C, int ldc,
    int M, int Nn, int Kk, int ep) {
  __shared__ float As[64][17];
  __shared__ float Ws[64][17];
  const int bm = blockIdx.y * 64, bn = blockIdx.x * 64;
  const int tid = threadIdx.x;
  const int tr = tid >> 4, tc = tid & 15;
  float acc[4][4];
#pragma unroll
  for (int i = 0; i < 4; i++)
#pragma unroll
    for (int j = 0; j < 4; j++) acc[i][j] = 0.f;

  for (int k0 = 0; k0 < Kk; k0 += 16) {
#pragma unroll
    for (int i = 0; i < 4; i++) {
      int idx = tid + i * 256;
      int r = idx >> 4, c = idx & 15;
      int gk = k0 + c;
      int gm = bm + r;
      As[r][c] = (gm < M && gk < Kk) ? A[(size_t)gm * lda + gk] : 0.f;
      int gn = bn + r;
      Ws[r][c] = (gn < Nn && gk < Kk) ? W[(size_t)gn * ldw + gk] : 0.f;
    }
    __syncthreads();
#pragma unroll
    for (int kk = 0; kk < 16; kk++) {
      float a0[4], w0[4];
#pragma unroll
      for (int i = 0; i < 4; i++) a0[i] = As[tr * 4 + i][kk];
#pragma unroll
      for (int j = 0; j < 4; j++) w0[j] = Ws[tc * 4 + j][kk];
#pragma unroll
      for (int i = 0; i < 4; i++)
#pragma unroll
        for (int j = 0; j < 4; j++) acc[i][j] += a0[i] * w0[j];
    }
    __syncthreads();
  }
#pragma unroll
  for (int i = 0; i < 4; i++) {
    int gm = bm + tr * 4 + i;
    if (gm >= M) continue;
#pragma unroll
    for (int j = 0; j < 4; j++) {
      int gn = bn + tc * 4 + j;
      if (gn >= Nn) continue;
      float v = acc[i][j];
      if (bias) v += bias[gn];
      if (res) v += res[(size_t)gm * ldc + gn];
      if (ep == 1) v = (v > 20.f) ? v : log1pf(expf(v));
      C[(size_t)gm * ldc + gn] = v;
    }
  }
}

// ---------------------------------------------------------------------------
// LayerNorm over last dim C (256 or 512). One 256-thread block per row.
__global__ __launch_bounds__(256) void k_ln(const float* __restrict__ X,
                                            const float* __restrict__ g,
                                            const float* __restrict__ bta,
                                            float* __restrict__ Y, int C) {
  const int row = blockIdx.x;
  const float* xr = X + (size_t)row * C;
  const int tid = threadIdx.x;
  const int per = C >> 8;  // 1 or 2
  float vals[2];
  float sum = 0.f, sumsq = 0.f;
  for (int i = 0; i < per; i++) {
    float v = xr[tid + i * 256];
    vals[i] = v;
    sum += v;
    sumsq += v * v;
  }
#pragma unroll
  for (int off = 1; off < 64; off <<= 1) {
    sum += __shfl_xor(sum, off, 64);
    sumsq += __shfl_xor(sumsq, off, 64);
  }
  __shared__ float s1[4], s2[4];
  int wid = tid >> 6, lane = tid & 63;
  if (lane == 0) { s1[wid] = sum; s2[wid] = sumsq; }
  __syncthreads();
  if (tid == 0) {
    float a = 0.f, c2 = 0.f;
    for (int w = 0; w < 4; w++) { a += s1[w]; c2 += s2[w]; }
    s1[0] = a; s2[0] = c2;
  }
  __syncthreads();
  float mean = s1[0] / (float)C;
  float var = s2[0] / (float)C - mean * mean;
  float rstd = rsqrtf(var + 1e-5f);
  for (int i = 0; i < per; i++) {
    int c = tid + i * 256;
    Y[(size_t)row * C + c] = (vals[i] - mean) * rstd * g[c] + bta[c];
  }
}

// ---------------------------------------------------------------------------
// Split xp (M,512) into u_f (M,256) = xp[:, :256] and u_b = flip_S(xp[:, 256:]).
__global__ __launch_bounds__(256) void k_split(const float* __restrict__ xp,
                                               float* __restrict__ uf,
                                               float* __restrict__ ub) {
  int idx = blockIdx.x * 256 + threadIdx.x;  // over M_*DH_
  if (idx >= M_ * DH_) return;
  int d = idx & (DH_ - 1);
  int row = idx >> 8;          // b*S+t
  int b = row >> 10, t = row & (S_ - 1);
  uf[idx] = xp[(size_t)row * D_ + d];
  ub[idx] = xp[((size_t)(b * S_ + (S_ - 1 - t))) * D_ + DH_ + d];
}

// Concat with back-flip: ycat (M,512) = [out_f[t], out_b[S-1-t]]
__global__ __launch_bounds__(256) void k_concat(const float* __restrict__ of,
                                                const float* __restrict__ ob,
                                                float* __restrict__ ycat) {
  int idx = blockIdx.x * 256 + threadIdx.x;  // over M_*DH_
  if (idx >= M_ * DH_) return;
  int d = idx & (DH_ - 1);
  int row = idx >> 8;
  int b = row >> 10, t = row & (S_ - 1);
  ycat[(size_t)row * D_ + d] = of[idx];
  ycat[(size_t)row * D_ + DH_ + d] = ob[((size_t)(b * S_ + (S_ - 1 - t))) * DH_ + d];
}

// ---------------------------------------------------------------------------
// Causal depthwise conv (K=4) + SiLU. Input: xz cols [0,512). Output xcv (M,512).
__global__ __launch_bounds__(256) void k_conv(const float* __restrict__ xz,
                                              const float* __restrict__ w,
                                              const float* __restrict__ cb,
                                              float* __restrict__ out) {
  int idx = blockIdx.x * 256 + threadIdx.x;  // over M_*DI_
  if (idx >= M_ * DI_) return;
  int d = idx & (DI_ - 1);
  int row = idx >> 9;
  int t = row & (S_ - 1);
  float acc = cb[d];
#pragma unroll
  for (int k = 0; k < 4; k++) {
    int dt_ = k - 3;
    if (t + dt_ >= 0)
      acc += w[d * 4 + k] * xz[(size_t)(row + dt_) * 1024 + d];
  }
  out[idx] = acc / (1.f + __expf(-acc));  // silu
}

// ---------------------------------------------------------------------------
// Chunked parallel scan. h[t] = a[t]*h[t-1] + u[t], a=exp(dt*A) diag in n.
// Pass A: per (b,chunk,d): local scan from 0 over T_ steps -> decay product
//         P[b][c][n][d], local end state hend[b][c][n][d].
__global__ __launch_bounds__(256) void k_scanA(
    const float* __restrict__ xz,    // dt at [row*1024 + d]
    const float* __restrict__ xc,    // (M,512)
    const float* __restrict__ dbl,   // (M,48): [dt16|B16|C16]
    const float* __restrict__ A_log, // (512,16)
    float* __restrict__ P,           // [2][CN_][16][512]
    float* __restrict__ hend) {
  const int blk = blockIdx.x;              // ((b*CN_)+c)*2 + half
  const int half = blk & 1;
  const int c = (blk >> 1) & (CN_ - 1);
  const int b = blk >> 7;                  // /(CN_*2)
  const int d = half * 256 + threadIdx.x;
  const int t0 = c * T_;
  __shared__ float Bs[T_][16];
  for (int i = threadIdx.x; i < T_ * 16; i += 256) {
    int t = i >> 4, n = i & 15;
    Bs[t][n] = dbl[(size_t)(b * S_ + t0 + t) * 48 + 16 + n];
  }
  float Av[16];
#pragma unroll
  for (int n = 0; n < 16; n++) Av[n] = -__expf(A_log[d * 16 + n]);
  float dtv[T_], xv[T_];
#pragma unroll
  for (int t = 0; t < T_; t++) {
    size_t row = (size_t)(b * S_ + t0 + t);
    dtv[t] = xz[row * 1024 + d];
    xv[t]  = xc[row * 512 + d];
  }
  __syncthreads();
  float h[16], Pr[16];
#pragma unroll
  for (int n = 0; n < 16; n++) { h[n] = 0.f; Pr[n] = 1.f; }
#pragma unroll
  for (int t = 0; t < T_; t++) {
    float dtx = dtv[t] * xv[t];
#pragma unroll
    for (int n = 0; n < 16; n++) {
      float a = __expf(dtv[t] * Av[n]);
      h[n] = a * h[n] + dtx * Bs[t][n];
      Pr[n] *= a;
    }
  }
  size_t base = (((size_t)b * CN_ + c) * 16) * 512 + d;
#pragma unroll
  for (int n = 0; n < 16; n++) {
    P[base + (size_t)n * 512] = Pr[n];
    hend[base + (size_t)n * 512] = h[n];
  }
}

// Pass B: serial prefix over chunks, one thread per (b,n,d) (diag in n).
// Hinit[b][c][n][d] = state entering chunk c.
__global__ __launch_bounds__(256) void k_scanB(
    const float* __restrict__ P,
    const float* __restrict__ hend,
    float* __restrict__ Hinit) {
  int idx = blockIdx.x * 256 + threadIdx.x;  // over 2*16*512
  if (idx >= 2 * 16 * 512) return;
  int d = idx & 511;
  int n = (idx >> 9) & 15;
  int b = idx >> 13;
  float H = 0.f;
  for (int c = 0; c < CN_; c++) {
    size_t o = (((size_t)b * CN_ + c) * 16 + n) * 512 + d;
    Hinit[o] = H;
    H = P[o] * H + hend[o];
  }
}

// Pass C: replay chunk with true initial state; fused D-residual + silu(z)
// gating; y written in place over the dt region of xz.
__global__ __launch_bounds__(256) void k_scanC(
    float* __restrict__ xz,          // (M,1024): dt|z ; y overwrites dt
    const float* __restrict__ xc,
    const float* __restrict__ dbl,
    const float* __restrict__ A_log,
    const float* __restrict__ Dp,
    const float* __restrict__ Hinit) {
  const int blk = blockIdx.x;
  const int half = blk & 1;
  const int c = (blk >> 1) & (CN_ - 1);
  const int b = blk >> 7;
  const int d = half * 256 + threadIdx.x;
  const int t0 = c * T_;
  __shared__ float Bs[T_][16], Cs[T_][16];
  for (int i = threadIdx.x; i < T_ * 16; i += 256) {
    int t = i >> 4, n = i & 15;
    size_t ro = (size_t)(b * S_ + t0 + t) * 48;
    Bs[t][n] = dbl[ro + 16 + n];
    Cs[t][n] = dbl[ro + 32 + n];
  }
  float Av[16];
#pragma unroll
  for (int n = 0; n < 16; n++) Av[n] = -__expf(A_log[d * 16 + n]);
  float Dd = Dp[d];
  float dtv[T_], xv[T_], zv[T_];
#pragma unroll
  for (int t = 0; t < T_; t++) {
    size_t row = (size_t)(b * S_ + t0 + t);
    dtv[t] = xz[row * 1024 + d];
    xv[t]  = xc[row * 512 + d];
    zv[t]  = xz[row * 1024 + 512 + d];
  }
  float h[16];
  size_t hbase = (((size_t)b * CN_ + c) * 16) * 512 + d;
#pragma unroll
  for (int n = 0; n < 16; n++) h[n] = Hinit[hbase + (size_t)n * 512];
  __syncthreads();
#pragma unroll
  for (int t = 0; t < T_; t++) {
    float dtx = dtv[t] * xv[t];
    float acc = 0.f;
#pragma unroll
    for (int n = 0; n < 16; n++) {
      float a = __expf(dtv[t] * Av[n]);
      h[n] = a * h[n] + dtx * Bs[t][n];
      acc += h[n] * Cs[t][n];
    }
    float sil = zv[t] / (1.f + __expf(-zv[t]));
    xz[(size_t)(b * S_ + t0 + t) * 1024 + d] = (acc + xv[t] * Dd) * sil;
  }
}

// ---------------------------------------------------------------------------
extern "C" void kernel_launch(void* const* d_in, const int* in_sizes, int n_in,
                              void* d_out, int out_size, void* d_ws, size_t ws_size,
                              hipStream_t stream) {
  const float* x     = (const float*)d_in[0];
  const float* ln_g  = (const float*)d_in[1];
  const float* ln_b  = (const float*)d_in[2];
  const float* inW   = (const float*)d_in[3];
  const float* convW = (const float*)d_in[4];
  const float* convB = (const float*)d_in[5];
  const float* xprojW= (const float*)d_in[6];
  const float* dtW   = (const float*)d_in[7];
  const float* dtB   = (const float*)d_in[8];
  const float* A_log = (const float*)d_in[9];
  const float* Dp    = (const float*)d_in[10];
  const float* outW  = (const float*)d_in[11];
  const float* ipW   = (const float*)d_in[12];
  const float* ipB   = (const float*)d_in[13];
  const float* opW   = (const float*)d_in[14];
  const float* opB   = (const float*)d_in[15];
  const float* fln_g = (const float*)d_in[16];
  const float* fln_b = (const float*)d_in[17];
  float* out = (float*)d_out;

  // ---- workspace (floats) ----
  float* w = (float*)d_ws;
  float* xz    = w;  w += (size_t)M_ * 1024;   // dt|z; scan y in place
  float* h_cur = w;  w += (size_t)M_ * D_;
  float* xp    = w;  w += (size_t)M_ * D_;     // also xn / ycat
  float* u_f   = w;  w += (size_t)M_ * DH_;
  float* u_b   = w;  w += (size_t)M_ * DH_;
  float* xcv   = w;  w += (size_t)M_ * DI_;
  float* dbl   = w;  w += (size_t)M_ * 48;
  float* Pbuf  = w;  w += (size_t)B_ * CN_ * 16 * 512;
  float* hend  = w;  w += (size_t)B_ * CN_ * 16 * 512;
  float* Hinit = w;  w += (size_t)B_ * CN_ * 16 * 512;
  float* xn    = xp;
  float* ycat  = xp;

  for (int li = 0; li < 2; li++) {
    const float* hin = (li == 0) ? x : h_cur;
    k_gemm<<<dim3(D_ / 64, M_ / 64), 256, 0, stream>>>(
        hin, D_, ipW + (size_t)li * D_ * D_, D_, ipB + (size_t)li * D_,
        nullptr, xp, D_, M_, D_, D_, 0);
    k_split<<<(M_ * DH_ + 255) / 256, 256, 0, stream>>>(xp, u_f, u_b);

    for (int j = 0; j < 2; j++) {
      size_t wi = (size_t)li * 2 + j;
      float* u = (j == 0) ? u_f : u_b;
      k_ln<<<M_, 256, 0, stream>>>(u, ln_g + wi * DH_, ln_b + wi * DH_, xn, DH_);
      k_gemm<<<dim3(1024 / 64, M_ / 64), 256, 0, stream>>>(
          xn, DH_, inW + wi * 1024 * DH_, DH_, nullptr, nullptr, xz, 1024,
          M_, 1024, DH_, 0);
      k_conv<<<(M_ * DI_ + 255) / 256, 256, 0, stream>>>(
          xz, convW + wi * DI_ * 4, convB + wi * DI_, xcv);
      k_gemm<<<dim3(1, M_ / 64), 256, 0, stream>>>(
          xcv, DI_, xprojW + wi * 48 * DI_, DI_, nullptr, nullptr, dbl, 48,
          M_, 48, DI_, 0);
      k_gemm<<<dim3(DI_ / 64, M_ / 64), 256, 0, stream>>>(
          dbl, 48, dtW + wi * DI_ * R_, R_, dtB + wi * DI_, nullptr, xz, 1024,
          M_, DI_, R_, 1);
      // chunked parallel scan
      k_scanA<<<B_ * CN_ * 2, 256, 0, stream>>>(
          xz, xcv, dbl, A_log + wi * DI_ * N_, Pbuf, hend);
      k_scanB<<<(2 * 16 * 512 + 255) / 256, 256, 0, stream>>>(Pbuf, hend, Hinit);
      k_scanC<<<B_ * CN_ * 2, 256, 0, stream>>>(
          xz, xcv, dbl, A_log + wi * DI_ * N_, Dp + wi * DI_, Hinit);
      // u = u + y @ outW.T
      k_gemm<<<dim3(DH_ / 64, M_ / 64), 256, 0, stream>>>(
          xz, 1024, outW + wi * DH_ * DI_, DI_, nullptr, u, u, DH_,
          M_, DH_, DI_, 0);
    }
    k_concat<<<(M_ * DH_ + 255) / 256, 256, 0, stream>>>(u_f, u_b, ycat);
    k_gemm<<<dim3(D_ / 64, M_ / 64), 256, 0, stream>>>(
        ycat, D_, opW + (size_t)li * D_ * D_, D_, opB + (size_t)li * D_,
        nullptr, h_cur, D_, M_, D_, D_, 0);
  }
  k_ln<<<M_, 256, 0, stream>>>(h_cur, fln_g, fln_b, out, D_);
}

// Round 5
// 735.771 us; speedup vs baseline: 4.5482x; 1.8533x over previous
//
#include <hip/hip_runtime.h>
#include <hip/hip_bf16.h>
#include <math.h>

typedef __hip_bfloat16 bf16;
typedef __attribute__((ext_vector_type(8))) short s8v;   // 8 bf16 (4 VGPRs)
typedef __attribute__((ext_vector_type(4))) float f4v;   // MFMA accumulator

// Problem constants (MambaEncoder: L=2, B=2, S=1024, D=512) — f32 in, f32 out.
#define B_ 2
#define S_ 1024
#define D_ 512
#define DH_ 256
#define DI_ 512
#define N_ 16
#define R_ 16
#define M_ 2048   // B_*S_
#define T_ 16     // scan chunk length
#define CN_ 64    // chunks per sequence

// ---------------------------------------------------------------------------
// f32 -> bf16 packed cast (n multiple of 4)
__global__ __launch_bounds__(256) void k_castv(const float* __restrict__ src,
                                               bf16* __restrict__ dst, int n) {
  int i = (blockIdx.x * 256 + threadIdx.x) * 4;
  if (i >= n) return;
  float4 v = *(const float4*)&src[i];
  dst[i + 0] = __float2bfloat16(v.x);
  dst[i + 1] = __float2bfloat16(v.y);
  dst[i + 2] = __float2bfloat16(v.z);
  dst[i + 3] = __float2bfloat16(v.w);
}

// ---------------------------------------------------------------------------
// MFMA bf16 GEMM: C[m,n] = sum_k A[m*K+k] * W[n*K+k] (+bias[n]) (+res[m*ldc+n])
// A: M x K bf16 packed. W: N x K bf16 packed. C: f32, stride ldc.
// M,N multiples of 64; K multiple of 32. res may alias C (owning lane only).
// 256 threads = 4 waves; tile 64x64; wave w owns n-strip [16w,16w+16).
__global__ __launch_bounds__(256) void k_mgemm(
    const bf16* __restrict__ A, const bf16* __restrict__ W,
    const float* __restrict__ bias, const float* res,
    float* C, int ldc, int K) {
  __shared__ short As[64][40];   // 80B rows: 16B-aligned frags, <=2-way conflicts
  __shared__ short Ws[64][40];
  const int bm = blockIdx.y * 64, bn = blockIdx.x * 64;
  const int tid = threadIdx.x;
  const int wave = tid >> 6, lane = tid & 63;
  const int q = lane >> 4, l15 = lane & 15;
  const int trow = tid >> 2, tcol = (tid & 3) * 8;

  f4v acc[4];
#pragma unroll
  for (int s = 0; s < 4; s++) acc[s] = (f4v){0.f, 0.f, 0.f, 0.f};

  for (int k0 = 0; k0 < K; k0 += 32) {
    // stage 64x32 bf16 tiles of A and W (16B per thread per matrix)
    uint4 av = *(const uint4*)&A[(size_t)(bm + trow) * K + k0 + tcol];
    uint4 wv = *(const uint4*)&W[(size_t)(bn + trow) * K + k0 + tcol];
    *(uint4*)&As[trow][tcol] = av;
    *(uint4*)&Ws[trow][tcol] = wv;
    __syncthreads();
    s8v bfrag = *(const s8v*)&Ws[wave * 16 + l15][q * 8];
#pragma unroll
    for (int s = 0; s < 4; s++) {
      s8v afrag = *(const s8v*)&As[s * 16 + l15][q * 8];
      acc[s] = __builtin_amdgcn_mfma_f32_16x16x32_bf16(afrag, bfrag, acc[s], 0, 0, 0);
    }
    __syncthreads();
  }
  // epilogue: D row(m) = q*4+r, col(n) = l15 within each 16x16 subtile
  const int col = bn + wave * 16 + l15;
  float bv = bias ? bias[col] : 0.f;
#pragma unroll
  for (int s = 0; s < 4; s++) {
    int row0 = bm + s * 16 + q * 4;
#pragma unroll
    for (int r = 0; r < 4; r++) {
      float v = acc[s][r] + bv;
      if (res) v += res[(size_t)(row0 + r) * ldc + col];
      C[(size_t)(row0 + r) * ldc + col] = v;
    }
  }
}

// ---------------------------------------------------------------------------
// f32 SIMT GEMM (kept for small shapes: xproj N=48, dt N=512/K=16 + softplus)
__global__ __launch_bounds__(256) void k_gemm(
    const float* __restrict__ A, int lda,
    const float* __restrict__ W, int ldw,
    const float* __restrict__ bias,
    const float* res,
    float* C, int ldc,
    int M, int Nn, int Kk, int ep) {
  __shared__ float Asm[64][17];
  __shared__ float Wsm[64][17];
  const int bm = blockIdx.y * 64, bn = blockIdx.x * 64;
  const int tid = threadIdx.x;
  const int tr = tid >> 4, tc = tid & 15;
  float acc[4][4];
#pragma unroll
  for (int i = 0; i < 4; i++)
#pragma unroll
    for (int j = 0; j < 4; j++) acc[i][j] = 0.f;

  for (int k0 = 0; k0 < Kk; k0 += 16) {
#pragma unroll
    for (int i = 0; i < 4; i++) {
      int idx = tid + i * 256;
      int r = idx >> 4, c = idx & 15;
      int gk = k0 + c;
      int gm = bm + r;
      Asm[r][c] = (gm < M && gk < Kk) ? A[(size_t)gm * lda + gk] : 0.f;
      int gn = bn + r;
      Wsm[r][c] = (gn < Nn && gk < Kk) ? W[(size_t)gn * ldw + gk] : 0.f;
    }
    __syncthreads();
#pragma unroll
    for (int kk = 0; kk < 16; kk++) {
      float a0[4], w0[4];
#pragma unroll
      for (int i = 0; i < 4; i++) a0[i] = Asm[tr * 4 + i][kk];
#pragma unroll
      for (int j = 0; j < 4; j++) w0[j] = Wsm[tc * 4 + j][kk];
#pragma unroll
      for (int i = 0; i < 4; i++)
#pragma unroll
        for (int j = 0; j < 4; j++) acc[i][j] += a0[i] * w0[j];
    }
    __syncthreads();
  }
#pragma unroll
  for (int i = 0; i < 4; i++) {
    int gm = bm + tr * 4 + i;
    if (gm >= M) continue;
#pragma unroll
    for (int j = 0; j < 4; j++) {
      int gn = bn + tc * 4 + j;
      if (gn >= Nn) continue;
      float v = acc[i][j];
      if (bias) v += bias[gn];
      if (res) v += res[(size_t)gm * ldc + gn];
      if (ep == 1) v = (v > 20.f) ? v : log1pf(expf(v));
      C[(size_t)gm * ldc + gn] = v;
    }
  }
}

// ---------------------------------------------------------------------------
// LayerNorm over last dim C (256 or 512). out_bf16: write bf16 (packed) or f32.
__global__ __launch_bounds__(256) void k_ln(const float* __restrict__ X,
                                            const float* __restrict__ g,
                                            const float* __restrict__ bta,
                                            void* __restrict__ Y, int C,
                                            int out_bf16) {
  const int row = blockIdx.x;
  const float* xr = X + (size_t)row * C;
  const int tid = threadIdx.x;
  const int per = C >> 8;  // 1 or 2
  float vals[2];
  float sum = 0.f, sumsq = 0.f;
  for (int i = 0; i < per; i++) {
    float v = xr[tid + i * 256];
    vals[i] = v;
    sum += v;
    sumsq += v * v;
  }
#pragma unroll
  for (int off = 1; off < 64; off <<= 1) {
    sum += __shfl_xor(sum, off, 64);
    sumsq += __shfl_xor(sumsq, off, 64);
  }
  __shared__ float s1[4], s2[4];
  int wid = tid >> 6, lane = tid & 63;
  if (lane == 0) { s1[wid] = sum; s2[wid] = sumsq; }
  __syncthreads();
  if (tid == 0) {
    float a = 0.f, c2 = 0.f;
    for (int w = 0; w < 4; w++) { a += s1[w]; c2 += s2[w]; }
    s1[0] = a; s2[0] = c2;
  }
  __syncthreads();
  float mean = s1[0] / (float)C;
  float var = s2[0] / (float)C - mean * mean;
  float rstd = rsqrtf(var + 1e-5f);
  for (int i = 0; i < per; i++) {
    int c = tid + i * 256;
    float y = (vals[i] - mean) * rstd * g[c] + bta[c];
    if (out_bf16)
      ((bf16*)Y)[(size_t)row * C + c] = __float2bfloat16(y);
    else
      ((float*)Y)[(size_t)row * C + c] = y;
  }
}

// ---------------------------------------------------------------------------
// Split xp (M,512) into u_f (M,256) = xp[:, :256] and u_b = flip_S(xp[:, 256:]).
__global__ __launch_bounds__(256) void k_split(const float* __restrict__ xp,
                                               float* __restrict__ uf,
                                               float* __restrict__ ub) {
  int idx = blockIdx.x * 256 + threadIdx.x;  // over M_*DH_
  if (idx >= M_ * DH_) return;
  int d = idx & (DH_ - 1);
  int row = idx >> 8;          // b*S+t
  int b = row >> 10, t = row & (S_ - 1);
  uf[idx] = xp[(size_t)row * D_ + d];
  ub[idx] = xp[((size_t)(b * S_ + (S_ - 1 - t))) * D_ + DH_ + d];
}

// Concat with back-flip -> bf16: ycat (M,512) = [o_f[t], o_b[S-1-t]]
__global__ __launch_bounds__(256) void k_concat(const float* __restrict__ of,
                                                const float* __restrict__ ob,
                                                bf16* __restrict__ ycat) {
  int idx = blockIdx.x * 256 + threadIdx.x;  // over M_*DH_
  if (idx >= M_ * DH_) return;
  int d = idx & (DH_ - 1);
  int row = idx >> 8;
  int b = row >> 10, t = row & (S_ - 1);
  ycat[(size_t)row * D_ + d] = __float2bfloat16(of[idx]);
  ycat[(size_t)row * D_ + DH_ + d] =
      __float2bfloat16(ob[((size_t)(b * S_ + (S_ - 1 - t))) * DH_ + d]);
}

// ---------------------------------------------------------------------------
// Causal depthwise conv (K=4) + SiLU. Input: xz cols [0,512). Output xcv (M,512).
__global__ __launch_bounds__(256) void k_conv(const float* __restrict__ xz,
                                              const float* __restrict__ w,
                                              const float* __restrict__ cb,
                                              float* __restrict__ out) {
  int idx = blockIdx.x * 256 + threadIdx.x;  // over M_*DI_
  if (idx >= M_ * DI_) return;
  int d = idx & (DI_ - 1);
  int row = idx >> 9;
  int t = row & (S_ - 1);
  float acc = cb[d];
#pragma unroll
  for (int k = 0; k < 4; k++) {
    int dt_ = k - 3;
    if (t + dt_ >= 0)
      acc += w[d * 4 + k] * xz[(size_t)(row + dt_) * 1024 + d];
  }
  out[idx] = acc / (1.f + __expf(-acc));  // silu
}

// ---------------------------------------------------------------------------
// Chunked parallel scan (exact decomposition of h[t]=a[t]h[t-1]+u[t]).
__global__ __launch_bounds__(256) void k_scanA(
    const float* __restrict__ xz,    // dt at [row*1024 + d]
    const float* __restrict__ xc,    // (M,512)
    const float* __restrict__ dbl,   // (M,48): [dt16|B16|C16]
    const float* __restrict__ A_log, // (512,16)
    float* __restrict__ P,           // [2][CN_][16][512]
    float* __restrict__ hend) {
  const int blk = blockIdx.x;
  const int half = blk & 1;
  const int c = (blk >> 1) & (CN_ - 1);
  const int b = blk >> 7;
  const int d = half * 256 + threadIdx.x;
  const int t0 = c * T_;
  __shared__ float Bs[T_][16];
  for (int i = threadIdx.x; i < T_ * 16; i += 256) {
    int t = i >> 4, n = i & 15;
    Bs[t][n] = dbl[(size_t)(b * S_ + t0 + t) * 48 + 16 + n];
  }
  float Av[16];
#pragma unroll
  for (int n = 0; n < 16; n++) Av[n] = -__expf(A_log[d * 16 + n]);
  float dtv[T_], xv[T_];
#pragma unroll
  for (int t = 0; t < T_; t++) {
    size_t row = (size_t)(b * S_ + t0 + t);
    dtv[t] = xz[row * 1024 + d];
    xv[t]  = xc[row * 512 + d];
  }
  __syncthreads();
  float h[16], Pr[16];
#pragma unroll
  for (int n = 0; n < 16; n++) { h[n] = 0.f; Pr[n] = 1.f; }
#pragma unroll
  for (int t = 0; t < T_; t++) {
    float dtx = dtv[t] * xv[t];
#pragma unroll
    for (int n = 0; n < 16; n++) {
      float a = __expf(dtv[t] * Av[n]);
      h[n] = a * h[n] + dtx * Bs[t][n];
      Pr[n] *= a;
    }
  }
  size_t base = (((size_t)b * CN_ + c) * 16) * 512 + d;
#pragma unroll
  for (int n = 0; n < 16; n++) {
    P[base + (size_t)n * 512] = Pr[n];
    hend[base + (size_t)n * 512] = h[n];
  }
}

// Pass B: serial prefix over chunks, one thread per (b,n,d). Hinit may alias P.
__global__ __launch_bounds__(256) void k_scanB(
    const float* __restrict__ P,
    const float* __restrict__ hend,
    float* __restrict__ Hinit) {
  int idx = blockIdx.x * 256 + threadIdx.x;  // over 2*16*512
  if (idx >= 2 * 16 * 512) return;
  int d = idx & 511;
  int n = (idx >> 9) & 15;
  int b = idx >> 13;
  float H = 0.f;
  for (int c = 0; c < CN_; c++) {
    size_t o = (((size_t)b * CN_ + c) * 16 + n) * 512 + d;
    float p = P[o];          // read before Hinit store (alias-safe)
    float he = hend[o];
    Hinit[o] = H;
    H = p * H + he;
  }
}

// Pass C: replay with true init; fused D-residual + silu(z); y -> bf16 packed.
__global__ __launch_bounds__(256) void k_scanC(
    const float* __restrict__ xz,    // (M,1024): dt|z
    const float* __restrict__ xc,
    const float* __restrict__ dbl,
    const float* __restrict__ A_log,
    const float* __restrict__ Dp,
    const float* __restrict__ Hinit,
    bf16* __restrict__ ybf) {        // (M,512)
  const int blk = blockIdx.x;
  const int half = blk & 1;
  const int c = (blk >> 1) & (CN_ - 1);
  const int b = blk >> 7;
  const int d = half * 256 + threadIdx.x;
  const int t0 = c * T_;
  __shared__ float Bs[T_][16], Cs[T_][16];
  for (int i = threadIdx.x; i < T_ * 16; i += 256) {
    int t = i >> 4, n = i & 15;
    size_t ro = (size_t)(b * S_ + t0 + t) * 48;
    Bs[t][n] = dbl[ro + 16 + n];
    Cs[t][n] = dbl[ro + 32 + n];
  }
  float Av[16];
#pragma unroll
  for (int n = 0; n < 16; n++) Av[n] = -__expf(A_log[d * 16 + n]);
  float Dd = Dp[d];
  float dtv[T_], xv[T_], zv[T_];
#pragma unroll
  for (int t = 0; t < T_; t++) {
    size_t row = (size_t)(b * S_ + t0 + t);
    dtv[t] = xz[row * 1024 + d];
    xv[t]  = xc[row * 512 + d];
    zv[t]  = xz[row * 1024 + 512 + d];
  }
  float h[16];
  size_t hbase = (((size_t)b * CN_ + c) * 16) * 512 + d;
#pragma unroll
  for (int n = 0; n < 16; n++) h[n] = Hinit[hbase + (size_t)n * 512];
  __syncthreads();
#pragma unroll
  for (int t = 0; t < T_; t++) {
    float dtx = dtv[t] * xv[t];
    float acc = 0.f;
#pragma unroll
    for (int n = 0; n < 16; n++) {
      float a = __expf(dtv[t] * Av[n]);
      h[n] = a * h[n] + dtx * Bs[t][n];
      acc += h[n] * Cs[t][n];
    }
    float sil = zv[t] / (1.f + __expf(-zv[t]));
    ybf[(size_t)(b * S_ + t0 + t) * 512 + d] =
        __float2bfloat16((acc + xv[t] * Dd) * sil);
  }
}

// ---------------------------------------------------------------------------
extern "C" void kernel_launch(void* const* d_in, const int* in_sizes, int n_in,
                              void* d_out, int out_size, void* d_ws, size_t ws_size,
                              hipStream_t stream) {
  const float* x     = (const float*)d_in[0];
  const float* ln_g  = (const float*)d_in[1];
  const float* ln_b  = (const float*)d_in[2];
  const float* inW   = (const float*)d_in[3];
  const float* convW = (const float*)d_in[4];
  const float* convB = (const float*)d_in[5];
  const float* xprojW= (const float*)d_in[6];
  const float* dtW   = (const float*)d_in[7];
  const float* dtB   = (const float*)d_in[8];
  const float* A_log = (const float*)d_in[9];
  const float* Dp    = (const float*)d_in[10];
  const float* outW  = (const float*)d_in[11];
  const float* ipW   = (const float*)d_in[12];
  const float* ipB   = (const float*)d_in[13];
  const float* opW   = (const float*)d_in[14];
  const float* opB   = (const float*)d_in[15];
  const float* fln_g = (const float*)d_in[16];
  const float* fln_b = (const float*)d_in[17];
  float* out = (float*)d_out;

  // ---- workspace ----
  float* w = (float*)d_ws;
  float* xz    = w;  w += (size_t)M_ * 1024;   // dt|z (f32)
  float* h_cur = w;  w += (size_t)M_ * D_;
  float* xp    = w;  w += (size_t)M_ * D_;
  float* u_f   = w;  w += (size_t)M_ * DH_;
  float* u_b   = w;  w += (size_t)M_ * DH_;
  float* xcv   = w;  w += (size_t)M_ * DI_;
  float* dbl   = w;  w += (size_t)M_ * 48;
  float* Pbuf  = w;  w += (size_t)B_ * CN_ * 16 * 512;   // also Hinit (aliased)
  float* hend  = w;  w += (size_t)B_ * CN_ * 16 * 512;
  float* Hinit = Pbuf;
  // bf16 region
  bf16* bw = (bf16*)w;
  bf16* xb    = bw;  bw += (size_t)M_ * D_;        // ip GEMM A (x or h_cur)
  bf16* xnb   = bw;  bw += (size_t)M_ * DH_;       // LN output
  bf16* ybf   = bw;  bw += (size_t)M_ * DI_;       // scan output
  bf16* ycatb = bw;  bw += (size_t)M_ * D_;        // concat output
  bf16* ipWb  = bw;  bw += (size_t)2 * D_ * D_;
  bf16* inWb  = bw;  bw += (size_t)4 * 1024 * DH_;
  bf16* outWb = bw;  bw += (size_t)4 * DH_ * DI_;
  bf16* opWb  = bw;  bw += (size_t)2 * D_ * D_;

  // ---- weight casts (once per launch) ----
  k_castv<<<(2 * D_ * D_ / 4 + 255) / 256, 256, 0, stream>>>(ipW, ipWb, 2 * D_ * D_);
  k_castv<<<(4 * 1024 * DH_ / 4 + 255) / 256, 256, 0, stream>>>(inW, inWb, 4 * 1024 * DH_);
  k_castv<<<(4 * DH_ * DI_ / 4 + 255) / 256, 256, 0, stream>>>(outW, outWb, 4 * DH_ * DI_);
  k_castv<<<(2 * D_ * D_ / 4 + 255) / 256, 256, 0, stream>>>(opW, opWb, 2 * D_ * D_);

  for (int li = 0; li < 2; li++) {
    // xb = bf16(x or h_cur); xp = xb @ ipW.T + ipB
    const float* hin = (li == 0) ? x : h_cur;
    k_castv<<<(M_ * D_ / 4 + 255) / 256, 256, 0, stream>>>(hin, xb, M_ * D_);
    k_mgemm<<<dim3(D_ / 64, M_ / 64), 256, 0, stream>>>(
        xb, ipWb + (size_t)li * D_ * D_, ipB + (size_t)li * D_, nullptr,
        xp, D_, D_);
    k_split<<<(M_ * DH_ + 255) / 256, 256, 0, stream>>>(xp, u_f, u_b);

    for (int j = 0; j < 2; j++) {
      size_t wi = (size_t)li * 2 + j;
      float* u = (j == 0) ? u_f : u_b;
      // xnb = bf16(LN(u))
      k_ln<<<M_, 256, 0, stream>>>(u, ln_g + wi * DH_, ln_b + wi * DH_,
                                   (void*)xnb, DH_, 1);
      // xz = xnb @ inW.T  (M,1024) f32
      k_mgemm<<<dim3(1024 / 64, M_ / 64), 256, 0, stream>>>(
          xnb, inWb + wi * 1024 * DH_, nullptr, nullptr, xz, 1024, DH_);
      // xcv = silu(causal_conv(xz[:, :512]))
      k_conv<<<(M_ * DI_ + 255) / 256, 256, 0, stream>>>(
          xz, convW + wi * DI_ * 4, convB + wi * DI_, xcv);
      // dbl = xcv @ xprojW.T  (M,48) f32
      k_gemm<<<dim3(1, M_ / 64), 256, 0, stream>>>(
          xcv, DI_, xprojW + wi * 48 * DI_, DI_, nullptr, nullptr, dbl, 48,
          M_, 48, DI_, 0);
      // dt = softplus(dbl[:, :16] @ dtW.T + dtB) -> xz cols [0,512)
      k_gemm<<<dim3(DI_ / 64, M_ / 64), 256, 0, stream>>>(
          dbl, 48, dtW + wi * DI_ * R_, R_, dtB + wi * DI_, nullptr, xz, 1024,
          M_, DI_, R_, 1);
      // chunked scan; C writes bf16 y
      k_scanA<<<B_ * CN_ * 2, 256, 0, stream>>>(
          xz, xcv, dbl, A_log + wi * DI_ * N_, Pbuf, hend);
      k_scanB<<<(2 * 16 * 512 + 255) / 256, 256, 0, stream>>>(Pbuf, hend, Hinit);
      k_scanC<<<B_ * CN_ * 2, 256, 0, stream>>>(
          xz, xcv, dbl, A_log + wi * DI_ * N_, Dp + wi * DI_, Hinit, ybf);
      // u = u + ybf @ outW.T
      k_mgemm<<<dim3(DH_ / 64, M_ / 64), 256, 0, stream>>>(
          ybf, outWb + wi * DH_ * DI_, nullptr, u, u, DH_, DI_);
    }
    // ycatb = bf16([o_f, flip(o_b)]); h_cur = ycatb @ opW.T + opB
    k_concat<<<(M_ * DH_ + 255) / 256, 256, 0, stream>>>(u_f, u_b, ycatb);
    k_mgemm<<<dim3(D_ / 64, M_ / 64), 256, 0, stream>>>(
        ycatb, opWb + (size_t)li * D_ * D_, opB + (size_t)li * D_, nullptr,
        h_cur, D_, D_);
  }
  // final LN -> f32 out
  k_ln<<<M_, 256, 0, stream>>>(h_cur, fln_g, fln_b, (void*)out, D_, 0);
}

// Round 6
// 460.758 us; speedup vs baseline: 7.2628x; 1.5969x over previous
//
#include <hip/hip_runtime.h>
#include <hip/hip_bf16.h>
#include <math.h>

typedef __hip_bfloat16 bf16;
typedef __attribute__((ext_vector_type(8))) short s8v;   // 8 bf16 (4 VGPRs)
typedef __attribute__((ext_vector_type(4))) float f4v;   // MFMA accumulator

// Problem constants (MambaEncoder: L=2, B=2, S=1024, D=512) — f32 in, f32 out.
#define B_ 2
#define S_ 1024
#define D_ 512
#define DH_ 256
#define DI_ 512
#define N_ 16
#define R_ 16
#define M_ 2048   // B_*S_
#define T_ 16     // scan chunk length
#define CN_ 64    // chunks per sequence
#define NC_ 576   // combined dt|B|C GEMM N (512 + 32 + 32 pad)

// ---------------------------------------------------------------------------
// f32 -> bf16 packed cast (n multiple of 4)
__global__ __launch_bounds__(256) void k_castv(const float* __restrict__ src,
                                               bf16* __restrict__ dst, int n) {
  int i = (blockIdx.x * 256 + threadIdx.x) * 4;
  if (i >= n) return;
  float4 v = *(const float4*)&src[i];
  dst[i + 0] = __float2bfloat16(v.x);
  dst[i + 1] = __float2bfloat16(v.y);
  dst[i + 2] = __float2bfloat16(v.z);
  dst[i + 3] = __float2bfloat16(v.w);
}

// ---------------------------------------------------------------------------
// Build combined weight Wcomb[wi][576][512] bf16:
//   rows 0..511  : (dtW @ xprojW[:16])[row][k]   (dt folded through xproj)
//   rows 512..543: xprojW[16 + row-512][k]       (B,C projection)
//   rows 544..575: 0
__global__ __launch_bounds__(256) void k_prep(const float* __restrict__ dtW,
                                              const float* __restrict__ xprojW,
                                              bf16* __restrict__ Wcomb) {
  int idx = blockIdx.x * 256 + threadIdx.x;  // over 4*576*512
  if (idx >= 4 * NC_ * 512) return;
  int k = idx & 511;
  int row = (idx >> 9) % NC_;
  int wi = idx / (NC_ * 512);
  float v = 0.f;
  if (row < 512) {
    const float* dw = dtW + (size_t)wi * 512 * 16 + row * 16;
    const float* xw = xprojW + (size_t)wi * 48 * 512;
#pragma unroll
    for (int r = 0; r < 16; r++) v += dw[r] * xw[r * 512 + k];
  } else if (row < 544) {
    v = xprojW[(size_t)wi * 48 * 512 + (16 + row - 512) * 512 + k];
  }
  Wcomb[idx] = __float2bfloat16(v);
}

// ---------------------------------------------------------------------------
// MFMA bf16 GEMM: C[m,n] = sum_k A[m*K+k]*W[n*K+k]; 64x64 tile, 4 waves.
// ep==0: +bias[n] (opt), +res[m*ldc+n] (opt; may alias C).
// ep==2: n<512 -> softplus(acc + bias[n]); n>=512 -> acc (B/C passthrough).
__global__ __launch_bounds__(256) void k_mgemm(
    const bf16* __restrict__ A, const bf16* __restrict__ W,
    const float* __restrict__ bias, const float* res,
    float* C, int ldc, int K, int ep) {
  __shared__ short As[64][40];   // 80B rows: <=2-way conflicts on frag reads
  __shared__ short Ws[64][40];
  const int bm = blockIdx.y * 64, bn = blockIdx.x * 64;
  const int tid = threadIdx.x;
  const int wave = tid >> 6, lane = tid & 63;
  const int q = lane >> 4, l15 = lane & 15;
  const int trow = tid >> 2, tcol = (tid & 3) * 8;

  f4v acc[4];
#pragma unroll
  for (int s = 0; s < 4; s++) acc[s] = (f4v){0.f, 0.f, 0.f, 0.f};

  for (int k0 = 0; k0 < K; k0 += 32) {
    uint4 av = *(const uint4*)&A[(size_t)(bm + trow) * K + k0 + tcol];
    uint4 wv = *(const uint4*)&W[(size_t)(bn + trow) * K + k0 + tcol];
    *(uint4*)&As[trow][tcol] = av;
    *(uint4*)&Ws[trow][tcol] = wv;
    __syncthreads();
    s8v bfrag = *(const s8v*)&Ws[wave * 16 + l15][q * 8];
#pragma unroll
    for (int s = 0; s < 4; s++) {
      s8v afrag = *(const s8v*)&As[s * 16 + l15][q * 8];
      acc[s] = __builtin_amdgcn_mfma_f32_16x16x32_bf16(afrag, bfrag, acc[s], 0, 0, 0);
    }
    __syncthreads();
  }
  const int col = bn + wave * 16 + l15;
  float bv = (bias && ep == 0) ? bias[col] : 0.f;
#pragma unroll
  for (int s = 0; s < 4; s++) {
    int row0 = bm + s * 16 + q * 4;
#pragma unroll
    for (int r = 0; r < 4; r++) {
      float v = acc[s][r];
      if (ep == 0) {
        v += bv;
        if (res) v += res[(size_t)(row0 + r) * ldc + col];
      } else {  // ep==2: combined dt|B|C epilogue
        if (col < 512) {
          v += bias[col];
          v = (v > 20.f) ? v : log1pf(expf(v));
        }
      }
      C[(size_t)(row0 + r) * ldc + col] = v;
    }
  }
}

// ---------------------------------------------------------------------------
// LayerNorm over last dim C (256 or 512). out_bf16: write bf16 or f32.
__global__ __launch_bounds__(256) void k_ln(const float* __restrict__ X,
                                            const float* __restrict__ g,
                                            const float* __restrict__ bta,
                                            void* __restrict__ Y, int C,
                                            int out_bf16) {
  const int row = blockIdx.x;
  const float* xr = X + (size_t)row * C;
  const int tid = threadIdx.x;
  const int per = C >> 8;  // 1 or 2
  float vals[2];
  float sum = 0.f, sumsq = 0.f;
  for (int i = 0; i < per; i++) {
    float v = xr[tid + i * 256];
    vals[i] = v;
    sum += v;
    sumsq += v * v;
  }
#pragma unroll
  for (int off = 1; off < 64; off <<= 1) {
    sum += __shfl_xor(sum, off, 64);
    sumsq += __shfl_xor(sumsq, off, 64);
  }
  __shared__ float s1[4], s2[4];
  int wid = tid >> 6, lane = tid & 63;
  if (lane == 0) { s1[wid] = sum; s2[wid] = sumsq; }
  __syncthreads();
  if (tid == 0) {
    float a = 0.f, c2 = 0.f;
    for (int w = 0; w < 4; w++) { a += s1[w]; c2 += s2[w]; }
    s1[0] = a; s2[0] = c2;
  }
  __syncthreads();
  float mean = s1[0] / (float)C;
  float var = s2[0] / (float)C - mean * mean;
  float rstd = rsqrtf(var + 1e-5f);
  for (int i = 0; i < per; i++) {
    int c = tid + i * 256;
    float y = (vals[i] - mean) * rstd * g[c] + bta[c];
    if (out_bf16)
      ((bf16*)Y)[(size_t)row * C + c] = __float2bfloat16(y);
    else
      ((float*)Y)[(size_t)row * C + c] = y;
  }
}

// ---------------------------------------------------------------------------
// Split xp (M,512) into u_f (M,256) = xp[:, :256] and u_b = flip_S(xp[:, 256:]).
__global__ __launch_bounds__(256) void k_split(const float* __restrict__ xp,
                                               float* __restrict__ uf,
                                               float* __restrict__ ub) {
  int idx = blockIdx.x * 256 + threadIdx.x;  // over M_*DH_
  if (idx >= M_ * DH_) return;
  int d = idx & (DH_ - 1);
  int row = idx >> 8;          // b*S+t
  int b = row >> 10, t = row & (S_ - 1);
  uf[idx] = xp[(size_t)row * D_ + d];
  ub[idx] = xp[((size_t)(b * S_ + (S_ - 1 - t))) * D_ + DH_ + d];
}

// Concat with back-flip -> bf16: ycat (M,512) = [o_f[t], o_b[S-1-t]]
__global__ __launch_bounds__(256) void k_concat(const float* __restrict__ of,
                                                const float* __restrict__ ob,
                                                bf16* __restrict__ ycat) {
  int idx = blockIdx.x * 256 + threadIdx.x;  // over M_*DH_
  if (idx >= M_ * DH_) return;
  int d = idx & (DH_ - 1);
  int row = idx >> 8;
  int b = row >> 10, t = row & (S_ - 1);
  ycat[(size_t)row * D_ + d] = __float2bfloat16(of[idx]);
  ycat[(size_t)row * D_ + DH_ + d] =
      __float2bfloat16(ob[((size_t)(b * S_ + (S_ - 1 - t))) * DH_ + d]);
}

// ---------------------------------------------------------------------------
// Causal depthwise conv (K=4) + SiLU. Writes f32 (scan) and bf16 (GEMM A).
__global__ __launch_bounds__(256) void k_conv(const float* __restrict__ xz,
                                              const float* __restrict__ w,
                                              const float* __restrict__ cb,
                                              float* __restrict__ outf,
                                              bf16* __restrict__ outb) {
  int idx = blockIdx.x * 256 + threadIdx.x;  // over M_*DI_
  if (idx >= M_ * DI_) return;
  int d = idx & (DI_ - 1);
  int row = idx >> 9;
  int t = row & (S_ - 1);
  float acc = cb[d];
#pragma unroll
  for (int k = 0; k < 4; k++) {
    int dt_ = k - 3;
    if (t + dt_ >= 0)
      acc += w[d * 4 + k] * xz[(size_t)(row + dt_) * 1024 + d];
  }
  float s = acc / (1.f + __expf(-acc));  // silu
  outf[idx] = s;
  outb[idx] = __float2bfloat16(s);
}

// ---------------------------------------------------------------------------
// Chunked parallel scan. dtbc (M,576) = [dt(512) | B(16) | C(16) | pad(32)].
__global__ __launch_bounds__(256) void k_scanA(
    const float* __restrict__ dtbc,
    const float* __restrict__ xc,    // (M,512) f32
    const float* __restrict__ A_log, // (512,16)
    float* __restrict__ P,           // [2][CN_][16][512]
    float* __restrict__ hend) {
  const int blk = blockIdx.x;
  const int half = blk & 1;
  const int c = (blk >> 1) & (CN_ - 1);
  const int b = blk >> 7;
  const int d = half * 256 + threadIdx.x;
  const int t0 = c * T_;
  __shared__ float Bs[T_][16];
  for (int i = threadIdx.x; i < T_ * 16; i += 256) {
    int t = i >> 4, n = i & 15;
    Bs[t][n] = dtbc[(size_t)(b * S_ + t0 + t) * NC_ + 512 + n];
  }
  float Av[16];
#pragma unroll
  for (int n = 0; n < 16; n++) Av[n] = -__expf(A_log[d * 16 + n]);
  float dtv[T_], xv[T_];
#pragma unroll
  for (int t = 0; t < T_; t++) {
    size_t row = (size_t)(b * S_ + t0 + t);
    dtv[t] = dtbc[row * NC_ + d];
    xv[t]  = xc[row * 512 + d];
  }
  __syncthreads();
  float h[16], Pr[16];
#pragma unroll
  for (int n = 0; n < 16; n++) { h[n] = 0.f; Pr[n] = 1.f; }
#pragma unroll
  for (int t = 0; t < T_; t++) {
    float dtx = dtv[t] * xv[t];
#pragma unroll
    for (int n = 0; n < 16; n++) {
      float a = __expf(dtv[t] * Av[n]);
      h[n] = a * h[n] + dtx * Bs[t][n];
      Pr[n] *= a;
    }
  }
  size_t base = (((size_t)b * CN_ + c) * 16) * 512 + d;
#pragma unroll
  for (int n = 0; n < 16; n++) {
    P[base + (size_t)n * 512] = Pr[n];
    hend[base + (size_t)n * 512] = h[n];
  }
}

// Pass B: serial prefix over chunks, one thread per (b,n,d). Hinit may alias P.
__global__ __launch_bounds__(256) void k_scanB(
    const float* __restrict__ P,
    const float* __restrict__ hend,
    float* __restrict__ Hinit) {
  int idx = blockIdx.x * 256 + threadIdx.x;  // over 2*16*512
  if (idx >= 2 * 16 * 512) return;
  int d = idx & 511;
  int n = (idx >> 9) & 15;
  int b = idx >> 13;
  float H = 0.f;
  for (int c = 0; c < CN_; c++) {
    size_t o = (((size_t)b * CN_ + c) * 16 + n) * 512 + d;
    float p = P[o];
    float he = hend[o];
    Hinit[o] = H;
    H = p * H + he;
  }
}

// Pass C: replay with true init; fused D-residual + silu(z); y -> bf16 packed.
__global__ __launch_bounds__(256) void k_scanC(
    const float* __restrict__ dtbc,  // dt | B | C
    const float* __restrict__ xz,    // z at cols [512,1024)
    const float* __restrict__ xc,
    const float* __restrict__ A_log,
    const float* __restrict__ Dp,
    const float* __restrict__ Hinit,
    bf16* __restrict__ ybf) {        // (M,512)
  const int blk = blockIdx.x;
  const int half = blk & 1;
  const int c = (blk >> 1) & (CN_ - 1);
  const int b = blk >> 7;
  const int d = half * 256 + threadIdx.x;
  const int t0 = c * T_;
  __shared__ float Bs[T_][16], Cs[T_][16];
  for (int i = threadIdx.x; i < T_ * 16; i += 256) {
    int t = i >> 4, n = i & 15;
    size_t ro = (size_t)(b * S_ + t0 + t) * NC_;
    Bs[t][n] = dtbc[ro + 512 + n];
    Cs[t][n] = dtbc[ro + 528 + n];
  }
  float Av[16];
#pragma unroll
  for (int n = 0; n < 16; n++) Av[n] = -__expf(A_log[d * 16 + n]);
  float Dd = Dp[d];
  float dtv[T_], xv[T_], zv[T_];
#pragma unroll
  for (int t = 0; t < T_; t++) {
    size_t row = (size_t)(b * S_ + t0 + t);
    dtv[t] = dtbc[row * NC_ + d];
    xv[t]  = xc[row * 512 + d];
    zv[t]  = xz[row * 1024 + 512 + d];
  }
  float h[16];
  size_t hbase = (((size_t)b * CN_ + c) * 16) * 512 + d;
#pragma unroll
  for (int n = 0; n < 16; n++) h[n] = Hinit[hbase + (size_t)n * 512];
  __syncthreads();
#pragma unroll
  for (int t = 0; t < T_; t++) {
    float dtx = dtv[t] * xv[t];
    float acc = 0.f;
#pragma unroll
    for (int n = 0; n < 16; n++) {
      float a = __expf(dtv[t] * Av[n]);
      h[n] = a * h[n] + dtx * Bs[t][n];
      acc += h[n] * Cs[t][n];
    }
    float sil = zv[t] / (1.f + __expf(-zv[t]));
    ybf[(size_t)(b * S_ + t0 + t) * 512 + d] =
        __float2bfloat16((acc + xv[t] * Dd) * sil);
  }
}

// ---------------------------------------------------------------------------
extern "C" void kernel_launch(void* const* d_in, const int* in_sizes, int n_in,
                              void* d_out, int out_size, void* d_ws, size_t ws_size,
                              hipStream_t stream) {
  const float* x     = (const float*)d_in[0];
  const float* ln_g  = (const float*)d_in[1];
  const float* ln_b  = (const float*)d_in[2];
  const float* inW   = (const float*)d_in[3];
  const float* convW = (const float*)d_in[4];
  const float* convB = (const float*)d_in[5];
  const float* xprojW= (const float*)d_in[6];
  const float* dtW   = (const float*)d_in[7];
  const float* dtB   = (const float*)d_in[8];
  const float* A_log = (const float*)d_in[9];
  const float* Dp    = (const float*)d_in[10];
  const float* outW  = (const float*)d_in[11];
  const float* ipW   = (const float*)d_in[12];
  const float* ipB   = (const float*)d_in[13];
  const float* opW   = (const float*)d_in[14];
  const float* opB   = (const float*)d_in[15];
  const float* fln_g = (const float*)d_in[16];
  const float* fln_b = (const float*)d_in[17];
  float* out = (float*)d_out;

  // ---- workspace ----
  float* w = (float*)d_ws;
  float* xz    = w;  w += (size_t)M_ * 1024;   // xc|z (f32)
  float* h_cur = w;  w += (size_t)M_ * D_;
  float* xp    = w;  w += (size_t)M_ * D_;
  float* u_f   = w;  w += (size_t)M_ * DH_;
  float* u_b   = w;  w += (size_t)M_ * DH_;
  float* xcv   = w;  w += (size_t)M_ * DI_;
  float* dtbc  = w;  w += (size_t)M_ * NC_;    // [dt|B|C|pad]
  float* Pbuf  = w;  w += (size_t)B_ * CN_ * 16 * 512;   // also Hinit
  float* hend  = w;  w += (size_t)B_ * CN_ * 16 * 512;
  float* Hinit = Pbuf;
  // bf16 region
  bf16* bw = (bf16*)w;
  bf16* xb    = bw;  bw += (size_t)M_ * D_;
  bf16* xnb   = bw;  bw += (size_t)M_ * DH_;
  bf16* ybf   = bw;  bw += (size_t)M_ * DI_;
  bf16* ycatb = bw;  bw += (size_t)M_ * D_;
  bf16* xcvb  = bw;  bw += (size_t)M_ * DI_;
  bf16* ipWb  = bw;  bw += (size_t)2 * D_ * D_;
  bf16* inWb  = bw;  bw += (size_t)4 * 1024 * DH_;
  bf16* outWb = bw;  bw += (size_t)4 * DH_ * DI_;
  bf16* opWb  = bw;  bw += (size_t)2 * D_ * D_;
  bf16* Wcomb = bw;  bw += (size_t)4 * NC_ * 512;

  // ---- weight prep (once per launch) ----
  k_castv<<<(2 * D_ * D_ / 4 + 255) / 256, 256, 0, stream>>>(ipW, ipWb, 2 * D_ * D_);
  k_castv<<<(4 * 1024 * DH_ / 4 + 255) / 256, 256, 0, stream>>>(inW, inWb, 4 * 1024 * DH_);
  k_castv<<<(4 * DH_ * DI_ / 4 + 255) / 256, 256, 0, stream>>>(outW, outWb, 4 * DH_ * DI_);
  k_castv<<<(2 * D_ * D_ / 4 + 255) / 256, 256, 0, stream>>>(opW, opWb, 2 * D_ * D_);
  k_prep<<<(4 * NC_ * 512 + 255) / 256, 256, 0, stream>>>(dtW, xprojW, Wcomb);

  for (int li = 0; li < 2; li++) {
    const float* hin = (li == 0) ? x : h_cur;
    k_castv<<<(M_ * D_ / 4 + 255) / 256, 256, 0, stream>>>(hin, xb, M_ * D_);
    k_mgemm<<<dim3(D_ / 64, M_ / 64), 256, 0, stream>>>(
        xb, ipWb + (size_t)li * D_ * D_, ipB + (size_t)li * D_, nullptr,
        xp, D_, D_, 0);
    k_split<<<(M_ * DH_ + 255) / 256, 256, 0, stream>>>(xp, u_f, u_b);

    for (int j = 0; j < 2; j++) {
      size_t wi = (size_t)li * 2 + j;
      float* u = (j == 0) ? u_f : u_b;
      k_ln<<<M_, 256, 0, stream>>>(u, ln_g + wi * DH_, ln_b + wi * DH_,
                                   (void*)xnb, DH_, 1);
      k_mgemm<<<dim3(1024 / 64, M_ / 64), 256, 0, stream>>>(
          xnb, inWb + wi * 1024 * DH_, nullptr, nullptr, xz, 1024, DH_, 0);
      k_conv<<<(M_ * DI_ + 255) / 256, 256, 0, stream>>>(
          xz, convW + wi * DI_ * 4, convB + wi * DI_, xcv, xcvb);
      // combined [softplus(dt) | B | C] GEMM
      k_mgemm<<<dim3(NC_ / 64, M_ / 64), 256, 0, stream>>>(
          xcvb, Wcomb + wi * NC_ * 512, dtB + wi * DI_, nullptr,
          dtbc, NC_, 512, 2);
      // chunked scan
      k_scanA<<<B_ * CN_ * 2, 256, 0, stream>>>(
          dtbc, xcv, A_log + wi * DI_ * N_, Pbuf, hend);
      k_scanB<<<(2 * 16 * 512 + 255) / 256, 256, 0, stream>>>(Pbuf, hend, Hinit);
      k_scanC<<<B_ * CN_ * 2, 256, 0, stream>>>(
          dtbc, xz, xcv, A_log + wi * DI_ * N_, Dp + wi * DI_, Hinit, ybf);
      // u = u + ybf @ outW.T
      k_mgemm<<<dim3(DH_ / 64, M_ / 64), 256, 0, stream>>>(
          ybf, outWb + wi * DH_ * DI_, nullptr, u, u, DH_, DI_, 0);
    }
    k_concat<<<(M_ * DH_ + 255) / 256, 256, 0, stream>>>(u_f, u_b, ycatb);
    k_mgemm<<<dim3(D_ / 64, M_ / 64), 256, 0, stream>>>(
        ycatb, opWb + (size_t)li * D_ * D_, opB + (size_t)li * D_, nullptr,
        h_cur, D_, D_, 0);
  }
  k_ln<<<M_, 256, 0, stream>>>(h_cur, fln_g, fln_b, (void*)out, D_, 0);
}

// Round 7
// 385.760 us; speedup vs baseline: 8.6748x; 1.1944x over previous
//
#include <hip/hip_runtime.h>
#include <hip/hip_bf16.h>
#include <math.h>

typedef __hip_bfloat16 bf16;
typedef __attribute__((ext_vector_type(8))) short s8v;   // 8 bf16 (4 VGPRs)
typedef __attribute__((ext_vector_type(4))) float f4v;   // MFMA accumulator

// Problem constants (MambaEncoder: L=2, B=2, S=1024, D=512) — f32 in, f32 out.
#define B_ 2
#define S_ 1024
#define D_ 512
#define DH_ 256
#define DI_ 512
#define N_ 16
#define R_ 16
#define M_ 2048   // B_*S_ (rows per direction); both dirs stacked -> 2*M_ rows
#define M2_ 4096
#define T_ 16     // scan chunk length
#define CN_ 64    // chunks per sequence
#define NC_ 576   // combined dt|B|C GEMM N (512 + 32 + 32 pad)

#define IPW_N (2*512*512)
#define INW_N (4*1024*256)
#define OUTW_N (4*256*512)
#define OPW_N (2*512*512)

// ---------------------------------------------------------------------------
// One-shot cast of all four big weight groups f32 -> bf16 (range-routed).
__global__ __launch_bounds__(256) void k_castall(
    const float* __restrict__ ipW, const float* __restrict__ inW,
    const float* __restrict__ outW, const float* __restrict__ opW,
    bf16* __restrict__ ipWb, bf16* __restrict__ inWb,
    bf16* __restrict__ outWb, bf16* __restrict__ opWb) {
  int i = (blockIdx.x * 256 + threadIdx.x) * 4;
  const float* s; bf16* dst; int off;
  if (i < IPW_N)                  { s = ipW;  dst = ipWb;  off = i; }
  else if (i < IPW_N + INW_N)     { s = inW;  dst = inWb;  off = i - IPW_N; }
  else if (i < IPW_N + INW_N + OUTW_N) { s = outW; dst = outWb; off = i - IPW_N - INW_N; }
  else if (i < IPW_N + INW_N + OUTW_N + OPW_N)
                                  { s = opW;  dst = opWb;  off = i - IPW_N - INW_N - OUTW_N; }
  else return;
  float4 v = *(const float4*)&s[off];
  dst[off + 0] = __float2bfloat16(v.x);
  dst[off + 1] = __float2bfloat16(v.y);
  dst[off + 2] = __float2bfloat16(v.z);
  dst[off + 3] = __float2bfloat16(v.w);
}

// f32 -> bf16 cast (x input)
__global__ __launch_bounds__(256) void k_castv(const float* __restrict__ src,
                                               bf16* __restrict__ dst, int n) {
  int i = (blockIdx.x * 256 + threadIdx.x) * 4;
  if (i >= n) return;
  float4 v = *(const float4*)&src[i];
  dst[i + 0] = __float2bfloat16(v.x);
  dst[i + 1] = __float2bfloat16(v.y);
  dst[i + 2] = __float2bfloat16(v.z);
  dst[i + 3] = __float2bfloat16(v.w);
}

// ---------------------------------------------------------------------------
// Build combined weight Wcomb[wi][576][512] bf16 (dt folded through xproj).
__global__ __launch_bounds__(256) void k_prep(const float* __restrict__ dtW,
                                              const float* __restrict__ xprojW,
                                              bf16* __restrict__ Wcomb) {
  int idx = blockIdx.x * 256 + threadIdx.x;  // over 4*576*512
  if (idx >= 4 * NC_ * 512) return;
  int k = idx & 511;
  int row = (idx >> 9) % NC_;
  int wi = idx / (NC_ * 512);
  float v = 0.f;
  if (row < 512) {
    const float* dw = dtW + (size_t)wi * 512 * 16 + row * 16;
    const float* xw = xprojW + (size_t)wi * 48 * 512;
#pragma unroll
    for (int r = 0; r < 16; r++) v += dw[r] * xw[r * 512 + k];
  } else if (row < 544) {
    v = xprojW[(size_t)wi * 48 * 512 + (16 + row - 512) * 512 + k];
  }
  Wcomb[idx] = __float2bfloat16(v);
}

// ---------------------------------------------------------------------------
// MFMA bf16 GEMM, 64x64 tile, 4 waves. Direction-batched: weight segment
// seg = bm>>11 selects W + seg*Wstr, bias + seg*bstr.
// ep0: +bias(opt) +res(opt, may alias C) -> C[row*ldc+col]
// ep2: col<512 -> softplus(acc+bias[col]); else passthrough (dt|B|C epilogue)
// ep3: ip+split: v=acc+bias; col<256 -> C[row*256+col];
//      col>=256 -> C[M_*256 + (row^1023)*256 + col-256]   (flip_S into u_b)
// ep4: op+concat: A staged from f32 u_f/u_b with flip+bf16 cvt;
//      epilogue v=acc+bias -> C f32 (h_cur) AND Cb bf16 (next-layer A)
__global__ __launch_bounds__(256) void k_mgemm(
    const bf16* __restrict__ A, const float* __restrict__ Af,
    const bf16* __restrict__ W, long Wstr,
    const float* __restrict__ bias, int bstr,
    const float* res,
    float* C, bf16* Cb, int ldc, int K, int ep) {
  __shared__ short As[64][40];   // 80B rows: <=2-way conflicts on frag reads
  __shared__ short Ws[64][40];
  const int bm = blockIdx.y * 64, bn = blockIdx.x * 64;
  const int seg = bm >> 11;
  const bf16* Wp = W + (size_t)seg * Wstr;
  const float* bp = bias ? bias + (size_t)seg * bstr : nullptr;
  const int tid = threadIdx.x;
  const int wave = tid >> 6, lane = tid & 63;
  const int q = lane >> 4, l15 = lane & 15;
  const int trow = tid >> 2, tcol = (tid & 3) * 8;

  f4v acc[4];
#pragma unroll
  for (int s = 0; s < 4; s++) acc[s] = (f4v){0.f, 0.f, 0.f, 0.f};

  for (int k0 = 0; k0 < K; k0 += 32) {
    if (ep == 4) {
      int ck = k0 + tcol;
      const float* src = (ck < 256)
          ? Af + (size_t)(bm + trow) * 256 + ck
          : Af + (size_t)M_ * 256 + (size_t)((bm + trow) ^ 1023) * 256 + (ck - 256);
      float4 f0 = *(const float4*)src;
      float4 f1 = *(const float4*)(src + 4);
      float fv[8] = {f0.x, f0.y, f0.z, f0.w, f1.x, f1.y, f1.z, f1.w};
      short tmp[8];
#pragma unroll
      for (int i = 0; i < 8; i++) {
        bf16 b = __float2bfloat16(fv[i]);
        tmp[i] = *(short*)&b;
      }
      *(uint4*)&As[trow][tcol] = *(uint4*)tmp;
    } else {
      *(uint4*)&As[trow][tcol] = *(const uint4*)&A[(size_t)(bm + trow) * K + k0 + tcol];
    }
    *(uint4*)&Ws[trow][tcol] = *(const uint4*)&Wp[(size_t)(bn + trow) * K + k0 + tcol];
    __syncthreads();
    s8v bfrag = *(const s8v*)&Ws[wave * 16 + l15][q * 8];
#pragma unroll
    for (int s = 0; s < 4; s++) {
      s8v afrag = *(const s8v*)&As[s * 16 + l15][q * 8];
      acc[s] = __builtin_amdgcn_mfma_f32_16x16x32_bf16(afrag, bfrag, acc[s], 0, 0, 0);
    }
    __syncthreads();
  }
  const int col = bn + wave * 16 + l15;
#pragma unroll
  for (int s = 0; s < 4; s++) {
#pragma unroll
    for (int r = 0; r < 4; r++) {
      int row = bm + s * 16 + q * 4 + r;
      float v = acc[s][r];
      if (ep == 0) {
        if (bp) v += bp[col];
        if (res) v += res[(size_t)row * ldc + col];
        C[(size_t)row * ldc + col] = v;
      } else if (ep == 2) {
        if (col < 512) {
          v += bp[col];
          v = (v > 20.f) ? v : log1pf(expf(v));
        }
        C[(size_t)row * ldc + col] = v;
      } else if (ep == 3) {
        v += bp[col];
        if (col < 256)
          C[(size_t)row * 256 + col] = v;
        else
          C[(size_t)M_ * 256 + (size_t)(row ^ 1023) * 256 + (col - 256)] = v;
      } else {  // ep4
        v += bp[col];
        C[(size_t)row * 512 + col] = v;
        Cb[(size_t)row * 512 + col] = __float2bfloat16(v);
      }
    }
  }
}

// ---------------------------------------------------------------------------
// LayerNorm over last dim C (256 or 512). gstr: gamma/beta offset for rows>=M_.
__global__ __launch_bounds__(256) void k_ln(const float* __restrict__ X,
                                            const float* __restrict__ g,
                                            const float* __restrict__ bta,
                                            int gstr, void* __restrict__ Y,
                                            int C, int out_bf16) {
  const int row = blockIdx.x;
  const int sel = (row >= M_) ? gstr : 0;
  const float* xr = X + (size_t)row * C;
  const int tid = threadIdx.x;
  const int per = C >> 8;  // 1 or 2
  float vals[2];
  float sum = 0.f, sumsq = 0.f;
  for (int i = 0; i < per; i++) {
    float v = xr[tid + i * 256];
    vals[i] = v;
    sum += v;
    sumsq += v * v;
  }
#pragma unroll
  for (int off = 1; off < 64; off <<= 1) {
    sum += __shfl_xor(sum, off, 64);
    sumsq += __shfl_xor(sumsq, off, 64);
  }
  __shared__ float s1[4], s2[4];
  int wid = tid >> 6, lane = tid & 63;
  if (lane == 0) { s1[wid] = sum; s2[wid] = sumsq; }
  __syncthreads();
  if (tid == 0) {
    float a = 0.f, c2 = 0.f;
    for (int w = 0; w < 4; w++) { a += s1[w]; c2 += s2[w]; }
    s1[0] = a; s2[0] = c2;
  }
  __syncthreads();
  float mean = s1[0] / (float)C;
  float var = s2[0] / (float)C - mean * mean;
  float rstd = rsqrtf(var + 1e-5f);
  for (int i = 0; i < per; i++) {
    int c = tid + i * 256;
    float y = (vals[i] - mean) * rstd * g[sel + c] + bta[sel + c];
    if (out_bf16)
      ((bf16*)Y)[(size_t)row * C + c] = __float2bfloat16(y);
    else
      ((float*)Y)[(size_t)row * C + c] = y;
  }
}

// ---------------------------------------------------------------------------
// Causal depthwise conv (K=4) + SiLU, direction-batched. Output bf16 only.
__global__ __launch_bounds__(256) void k_conv(const float* __restrict__ xz,
                                              const float* __restrict__ convW,
                                              const float* __restrict__ convB,
                                              bf16* __restrict__ outb) {
  int idx = blockIdx.x * 256 + threadIdx.x;  // over M2_*DI_
  if (idx >= M2_ * DI_) return;
  int d = idx & (DI_ - 1);
  int row = idx >> 9;          // 0..4095
  int seg = row >> 11;         // direction
  int t = row & (S_ - 1);
  const float* w = convW + seg * DI_ * 4;
  float acc = convB[seg * DI_ + d];
#pragma unroll
  for (int k = 0; k < 4; k++) {
    int dt_ = k - 3;
    if (t + dt_ >= 0)
      acc += w[d * 4 + k] * xz[(size_t)(row + dt_) * 1024 + d];
  }
  float s = acc / (1.f + __expf(-acc));  // silu
  outb[idx] = __float2bfloat16(s);
}

// ---------------------------------------------------------------------------
// Chunked parallel scan over 4 sequences (2 batch x 2 direction).
// dtbc (M2_,576) = [dt(512) | B(16) | C(16) | pad]. x as bf16 (xcvb).
__global__ __launch_bounds__(256) void k_scanA(
    const float* __restrict__ dtbc,
    const bf16* __restrict__ xcb,
    const float* __restrict__ A_log, // layer base; +dir*512*16
    float* __restrict__ P,           // [4][CN_][16][512]
    float* __restrict__ hend) {
  const int blk = blockIdx.x;        // 4*64*2
  const int half = blk & 1;
  const int c = (blk >> 1) & (CN_ - 1);
  const int s = blk >> 7;            // sequence 0..3
  const int dir = s >> 1;
  const int d = half * 256 + threadIdx.x;
  const int r0 = s * S_ + c * T_;
  __shared__ float Bs[T_][16];
  for (int i = threadIdx.x; i < T_ * 16; i += 256) {
    int t = i >> 4, n = i & 15;
    Bs[t][n] = dtbc[(size_t)(r0 + t) * NC_ + 512 + n];
  }
  float Av[16];
#pragma unroll
  for (int n = 0; n < 16; n++) Av[n] = -__expf(A_log[dir * DI_ * 16 + d * 16 + n]);
  float dtv[T_], xv[T_];
#pragma unroll
  for (int t = 0; t < T_; t++) {
    size_t row = (size_t)(r0 + t);
    dtv[t] = dtbc[row * NC_ + d];
    xv[t]  = __bfloat162float(xcb[row * 512 + d]);
  }
  __syncthreads();
  float h[16], Pr[16];
#pragma unroll
  for (int n = 0; n < 16; n++) { h[n] = 0.f; Pr[n] = 1.f; }
#pragma unroll
  for (int t = 0; t < T_; t++) {
    float dtx = dtv[t] * xv[t];
#pragma unroll
    for (int n = 0; n < 16; n++) {
      float a = __expf(dtv[t] * Av[n]);
      h[n] = a * h[n] + dtx * Bs[t][n];
      Pr[n] *= a;
    }
  }
  size_t base = (((size_t)s * CN_ + c) * 16) * 512 + d;
#pragma unroll
  for (int n = 0; n < 16; n++) {
    P[base + (size_t)n * 512] = Pr[n];
    hend[base + (size_t)n * 512] = h[n];
  }
}

// Pass B: serial prefix over chunks, one thread per (s,n,d). Hinit aliases P.
__global__ __launch_bounds__(256) void k_scanB(
    const float* __restrict__ P,
    const float* __restrict__ hend,
    float* __restrict__ Hinit) {
  int idx = blockIdx.x * 256 + threadIdx.x;  // over 4*16*512
  if (idx >= 4 * 16 * 512) return;
  int d = idx & 511;
  int n = (idx >> 9) & 15;
  int s = idx >> 13;
  float H = 0.f;
  for (int c = 0; c < CN_; c++) {
    size_t o = (((size_t)s * CN_ + c) * 16 + n) * 512 + d;
    float p = P[o];
    float he = hend[o];
    Hinit[o] = H;
    H = p * H + he;
  }
}

// Pass C: replay with true init; fused D-residual + silu(z); y -> bf16.
__global__ __launch_bounds__(256) void k_scanC(
    const float* __restrict__ dtbc,
    const float* __restrict__ xz,    // z at cols [512,1024)
    const bf16* __restrict__ xcb,
    const float* __restrict__ A_log,
    const float* __restrict__ Dp,    // layer base; +dir*512
    const float* __restrict__ Hinit,
    bf16* __restrict__ ybf) {        // (M2_,512)
  const int blk = blockIdx.x;
  const int half = blk & 1;
  const int c = (blk >> 1) & (CN_ - 1);
  const int s = blk >> 7;
  const int dir = s >> 1;
  const int d = half * 256 + threadIdx.x;
  const int r0 = s * S_ + c * T_;
  __shared__ float Bs[T_][16], Cs[T_][16];
  for (int i = threadIdx.x; i < T_ * 16; i += 256) {
    int t = i >> 4, n = i & 15;
    size_t ro = (size_t)(r0 + t) * NC_;
    Bs[t][n] = dtbc[ro + 512 + n];
    Cs[t][n] = dtbc[ro + 528 + n];
  }
  float Av[16];
#pragma unroll
  for (int n = 0; n < 16; n++) Av[n] = -__expf(A_log[dir * DI_ * 16 + d * 16 + n]);
  float Dd = Dp[dir * DI_ + d];
  float dtv[T_], xv[T_], zv[T_];
#pragma unroll
  for (int t = 0; t < T_; t++) {
    size_t row = (size_t)(r0 + t);
    dtv[t] = dtbc[row * NC_ + d];
    xv[t]  = __bfloat162float(xcb[row * 512 + d]);
    zv[t]  = xz[row * 1024 + 512 + d];
  }
  float h[16];
  size_t hbase = (((size_t)s * CN_ + c) * 16) * 512 + d;
#pragma unroll
  for (int n = 0; n < 16; n++) h[n] = Hinit[hbase + (size_t)n * 512];
  __syncthreads();
#pragma unroll
  for (int t = 0; t < T_; t++) {
    float dtx = dtv[t] * xv[t];
    float acc = 0.f;
#pragma unroll
    for (int n = 0; n < 16; n++) {
      float a = __expf(dtv[t] * Av[n]);
      h[n] = a * h[n] + dtx * Bs[t][n];
      acc += h[n] * Cs[t][n];
    }
    float sil = zv[t] / (1.f + __expf(-zv[t]));
    ybf[(size_t)(r0 + t) * 512 + d] =
        __float2bfloat16((acc + xv[t] * Dd) * sil);
  }
}

// ---------------------------------------------------------------------------
extern "C" void kernel_launch(void* const* d_in, const int* in_sizes, int n_in,
                              void* d_out, int out_size, void* d_ws, size_t ws_size,
                              hipStream_t stream) {
  const float* x     = (const float*)d_in[0];
  const float* ln_g  = (const float*)d_in[1];
  const float* ln_b  = (const float*)d_in[2];
  const float* inW   = (const float*)d_in[3];
  const float* convW = (const float*)d_in[4];
  const float* convB = (const float*)d_in[5];
  const float* xprojW= (const float*)d_in[6];
  const float* dtW   = (const float*)d_in[7];
  const float* dtB   = (const float*)d_in[8];
  const float* A_log = (const float*)d_in[9];
  const float* Dp    = (const float*)d_in[10];
  const float* outW  = (const float*)d_in[11];
  const float* ipW   = (const float*)d_in[12];
  const float* ipB   = (const float*)d_in[13];
  const float* opW   = (const float*)d_in[14];
  const float* opB   = (const float*)d_in[15];
  const float* fln_g = (const float*)d_in[16];
  const float* fln_b = (const float*)d_in[17];
  float* out = (float*)d_out;

  // ---- workspace (ws_size ~268 MB per profile; we use ~71 MB) ----
  float* w = (float*)d_ws;
  float* xz2   = w;  w += (size_t)M2_ * 1024;  // [xc | z] f32, both dirs
  float* h_cur = w;  w += (size_t)M_ * D_;
  float* u_f   = w;  w += (size_t)M2_ * DH_;   // u_f rows [0,M), u_b rows [M,2M)
  float* dtbc2 = w;  w += (size_t)M2_ * NC_;
  float* Pbuf  = w;  w += (size_t)4 * CN_ * 16 * 512;  // also Hinit
  float* hend  = w;  w += (size_t)4 * CN_ * 16 * 512;
  float* Hinit = Pbuf;
  bf16* bw = (bf16*)w;
  bf16* xb    = bw;  bw += (size_t)M_ * D_;
  bf16* xnb2  = bw;  bw += (size_t)M2_ * DH_;
  bf16* xcvb2 = bw;  bw += (size_t)M2_ * DI_;
  bf16* ybf2  = bw;  bw += (size_t)M2_ * DI_;
  bf16* ipWb  = bw;  bw += (size_t)IPW_N;
  bf16* inWb  = bw;  bw += (size_t)INW_N;
  bf16* outWb = bw;  bw += (size_t)OUTW_N;
  bf16* opWb  = bw;  bw += (size_t)OPW_N;
  bf16* Wcomb = bw;  bw += (size_t)4 * NC_ * 512;

  // ---- weight prep (2 dispatches) ----
  int tot = IPW_N + INW_N + OUTW_N + OPW_N;
  k_castall<<<(tot / 4 + 255) / 256, 256, 0, stream>>>(
      ipW, inW, outW, opW, ipWb, inWb, outWb, opWb);
  k_prep<<<(4 * NC_ * 512 + 255) / 256, 256, 0, stream>>>(dtW, xprojW, Wcomb);
  k_castv<<<(M_ * D_ / 4 + 255) / 256, 256, 0, stream>>>(x, xb, M_ * D_);

  for (int li = 0; li < 2; li++) {
    // ip + fused split: xb @ ipW.T + ipB -> u_f / flipped u_b
    k_mgemm<<<dim3(8, 32), 256, 0, stream>>>(
        xb, nullptr, ipWb + (size_t)li * D_ * D_, 0,
        ipB + (size_t)li * D_, 0, nullptr, u_f, nullptr, 256, D_, 3);
    // LN both dirs -> xnb2 bf16
    k_ln<<<M2_, 256, 0, stream>>>(u_f, ln_g + li * 2 * DH_, ln_b + li * 2 * DH_,
                                  DH_, (void*)xnb2, DH_, 1);
    // xz = xn @ inW.T  (both dirs; seg-selected weights)
    k_mgemm<<<dim3(16, 64), 256, 0, stream>>>(
        xnb2, nullptr, inWb + (size_t)li * 2 * 1024 * DH_, (long)1024 * DH_,
        nullptr, 0, nullptr, xz2, nullptr, 1024, DH_, 0);
    // conv + silu -> xcvb2 bf16
    k_conv<<<(M2_ * DI_ + 255) / 256, 256, 0, stream>>>(
        xz2, convW + li * 2 * DI_ * 4, convB + li * 2 * DI_, xcvb2);
    // combined [softplus(dt) | B | C] GEMM
    k_mgemm<<<dim3(9, 64), 256, 0, stream>>>(
        xcvb2, nullptr, Wcomb + (size_t)li * 2 * NC_ * 512, (long)NC_ * 512,
        dtB + li * 2 * DI_, DI_, nullptr, dtbc2, nullptr, NC_, 512, 2);
    // chunked scan (4 sequences)
    k_scanA<<<4 * CN_ * 2, 256, 0, stream>>>(
        dtbc2, xcvb2, A_log + (size_t)li * 2 * DI_ * N_, Pbuf, hend);
    k_scanB<<<(4 * 16 * 512 + 255) / 256, 256, 0, stream>>>(Pbuf, hend, Hinit);
    k_scanC<<<4 * CN_ * 2, 256, 0, stream>>>(
        dtbc2, xz2, xcvb2, A_log + (size_t)li * 2 * DI_ * N_,
        Dp + (size_t)li * 2 * DI_, Hinit, ybf2);
    // u += y @ outW.T  (both dirs, res alias)
    k_mgemm<<<dim3(4, 64), 256, 0, stream>>>(
        ybf2, nullptr, outWb + (size_t)li * 2 * DH_ * DI_, (long)DH_ * DI_,
        nullptr, 0, u_f, u_f, nullptr, 256, DI_, 0);
    // op + fused concat(+flip) + bias; writes h_cur f32 and xb bf16
    k_mgemm<<<dim3(8, 32), 256, 0, stream>>>(
        nullptr, u_f, opWb + (size_t)li * D_ * D_, 0,
        opB + (size_t)li * D_, 0, nullptr, h_cur, xb, 512, D_, 4);
  }
  // final LN -> f32 out
  k_ln<<<M_, 256, 0, stream>>>(h_cur, fln_g, fln_b, 0, (void*)out, D_, 0);
}